// Round 9
// baseline (172.244 us; speedup 1.0000x reference)
//
#include <hip/hip_runtime.h>
#include <math.h>

#define NB 4
#define PP 256
#define CC 151
#define RR 51
#define CM 160                 // padded C (5 tiles of 32)
#define KS 64                  // split-K: 4 i's per block
#define NROW (NB*PP)           // 1024
#define RELTOT (NB*PP*PP*RR)   // 13,369,344 floats
#define ALIM (RELTOT - 8)
#define MLB 10240              // halves per l per mat: 8 oct * 160 c * 8 j

typedef _Float16 half8 __attribute__((ext_vector_type(8)));
typedef float floatx16 __attribute__((ext_vector_type(16)));

// ws layout (bytes): m1, m2, part
#define OFF_M1 ((size_t)0)
#define OFF_M2 (OFF_M1 + (size_t)CC*MLB*2)     // +3,092,480
#define OFF_PT (OFF_M2 + (size_t)CC*MLB*2)     // part: 64*1024*160*4 = 41.9 MB

// ---------------------------------------------------------------------------
// K1: streaming M layout. m1[l][oct][c][j] = w_r*M[l][c][oct*8+j],
// m2[l][oct][c][j] = w_r*M[c][l][oct*8+j]; r=oct*8+j; w_0=0.5 else 0.25;
// zero for r>=51 or c>=151 (zero rows make A's pad slots don't-care).
// ---------------------------------------------------------------------------
__global__ __launch_bounds__(256) void prep_kernel(const float* __restrict__ M,
                                                   _Float16* __restrict__ m1,
                                                   _Float16* __restrict__ m2,
                                                   float* __restrict__ out) {
    const int l = blockIdx.x;      // 0..150
    const int mat = blockIdx.y;    // 0,1
    if (l == 0 && mat == 0 && threadIdx.x == 0) *out = 0.f;
    _Float16* dst = (mat ? m2 : m1) + (size_t)l * MLB;
    for (int e = threadIdx.x; e < MLB; e += 256) {
        int oct = e / 1280;
        int rem = e - oct * 1280;
        int c = rem >> 3, j = rem & 7;
        int r = oct * 8 + j;
        float v = 0.f;
        if (r < RR && c < CC) {
            size_t src = ((size_t)(mat ? c * CC + l : l * CC + c)) * RR + r;
            v = (r == 0 ? 0.5f : 0.25f) * M[src];
        }
        dst[e] = (_Float16)v;
    }
}

// ---------------------------------------------------------------------------
// K2 (fused transpose+GEMM, 32x32x16 MFMA, dual wave-group):
// part[ks][q][c] = sum_{i in chunk, r} rel[n,i,q,r]*w_r*M[lab_i,c,r]   (mat0)
//                                    + rel[n,q,i,r]*w_r*M[c,lab_i,r]   (mat1)
// 512-thread blocks: waves 0-3 do mat0, waves 4-7 do mat1 (independent
// B double-buffers; 2x the concurrent VMEM streams of the 256-thr version
// -> raises achieved HBM BW). 16 k16-steps (4 i x 4 t). A direct per-lane
// strided fp32 loads (reg double-buffered); diagonal zeroed; pad r-slots
// hit zero B rows. Epilogue: group1 acc merged via LDS, group0 writes part.
// Grid 512 = 4 img x 2 rowblk x 64 ks; 2 blocks/CU = 16 waves/CU.
// ---------------------------------------------------------------------------
__global__ __launch_bounds__(512, 4) void gemm_kernel(const float* __restrict__ rel,
                                                      const _Float16* __restrict__ m1,
                                                      const _Float16* __restrict__ m2,
                                                      const int* __restrict__ labels,
                                                      float* __restrict__ part) {
    __shared__ _Float16 Bt[2][2][2560];    // [group][buf] 5 KB tiles = 20 KB
    const int tid  = threadIdx.x;          // 0..511
    const int ks   = blockIdx.x & 63;
    const int rbk  = (blockIdx.x >> 6) & 1;
    const int n    = blockIdx.x >> 7;
    const int wave = tid >> 6;             // 0..7
    const int grp  = wave >> 2;            // 0: mat0, 1: mat1
    const int wg   = wave & 3;             // wave within group
    const int lane = tid & 63;
    const int m32  = lane & 31, kh = lane >> 5;
    const int gtid = tid & 255;            // thread within group
    const int i0   = ks * 4;
    const int rowimg = rbk * 128 + wg * 32 + m32;   // lane's output row q

    int labs[4];
    #pragma unroll
    for (int j = 0; j < 4; ++j) labs[j] = labels[n * PP + i0 + j];

    const _Float16* mbase = grp ? m2 : m1;

    floatx16 acc[5];
    #pragma unroll
    for (int ct = 0; ct < 5; ++ct)
        #pragma unroll
        for (int r2 = 0; r2 < 16; ++r2) acc[ct][r2] = 0.f;

    // step h in [0,16): il = h>>2 (i), t = h&3 (k16 tile). Each group stages
    // its own 5 KB tile (320 contiguous 16B chunks) with 256 group-threads.
    auto stageB = [&](int h, int buf) {
        const int il = h >> 2, t = h & 3;
        const _Float16* base = mbase + (size_t)labs[il] * MLB + t * 2560;
        __builtin_amdgcn_global_load_lds(
            (const __attribute__((address_space(1))) unsigned int*)(base + (size_t)gtid * 8),
            (__attribute__((address_space(3))) unsigned int*)(&Bt[grp][buf][(size_t)gtid * 8]),
            16, 0, 0);
        if (gtid < 64) {
            int s = 256 + gtid;
            __builtin_amdgcn_global_load_lds(
                (const __attribute__((address_space(1))) unsigned int*)(base + (size_t)s * 8),
                (__attribute__((address_space(3))) unsigned int*)(&Bt[grp][buf][(size_t)s * 8]),
                16, 0, 0);
        }
    };
    // this lane's 8 fp32 A elements for step h (own mat only)
    auto loadA = [&](int h, float* v) {
        const int il = h >> 2, t = h & 3;
        const int i = i0 + il;
        const int r0 = t * 16 + kh * 8;
        int idx = grp ? ((n * PP + rowimg) * PP + i) * RR + r0
                      : ((n * PP + i) * PP + rowimg) * RR + r0;
        idx = min(idx, ALIM);   // clamp reachable only on i==q==255 diag (zeroed)
        const float* p = rel + idx;
        #pragma unroll
        for (int j = 0; j < 8; ++j) v[j] = p[j];
    };

    stageB(0, 0);
    float av[8];
    loadA(0, av);

    for (int h = 0; h < 16; ++h) {
        __syncthreads();                   // Bt[grp][h&1] staged >=1 iter ago
        if (h < 15) stageB(h + 1, (h + 1) & 1);
        float avn[8];
        if (h < 15) loadA(h + 1, avn);

        const bool dz = (i0 + (h >> 2)) == rowimg;   // diagonal i == q
        half8 a;
        #pragma unroll
        for (int j = 0; j < 8; ++j) a[j] = (_Float16)(dz ? 0.f : av[j]);

        const _Float16* bb = &Bt[grp][h & 1][(size_t)(kh * 160 + m32) * 8];
        #pragma unroll
        for (int ct = 0; ct < 5; ++ct) {
            half8 b = *(const half8*)(bb + ct * 256);
            acc[ct] = __builtin_amdgcn_mfma_f32_32x32x16_f16(a, b, acc[ct], 0, 0, 0);
        }
        #pragma unroll
        for (int j = 0; j < 8; ++j) av[j] = avn[j];
    }

    // Epilogue: merge group1 into group0 via LDS, one 32-c tile at a time.
    // C/D 32x32 layout (m74/m101): col = m32, row = (reg&3)+8*(reg>>2)+4*kh.
    float* ep = (float*)Bt;                // 20 KB >= 4096 floats
    float* pb = part + ((size_t)ks * NROW + n * PP + rbk * 128) * CM;
    #pragma unroll
    for (int ct = 0; ct < 5; ++ct) {
        __syncthreads();
        if (grp == 1) {
            #pragma unroll
            for (int reg = 0; reg < 16; ++reg) {
                int rowD = (reg & 3) + 8 * (reg >> 2) + 4 * kh;
                ep[(size_t)(wg * 32 + rowD) * 32 + m32] = acc[ct][reg];
            }
        }
        __syncthreads();
        if (grp == 0) {
            #pragma unroll
            for (int reg = 0; reg < 16; ++reg) {
                int rowD = (reg & 3) + 8 * (reg >> 2) + 4 * kh;
                int rloc = wg * 32 + rowD;
                pb[(size_t)rloc * CM + ct * 32 + m32] =
                    acc[ct][reg] + ep[(size_t)rloc * 32 + m32];
            }
        }
    }
}

// ---------------------------------------------------------------------------
// K3: theta[row][c] = sum_ks part; loss = lse(theta) - theta[lab]; mean.
// ---------------------------------------------------------------------------
__global__ __launch_bounds__(256) void reduce_loss_kernel(const float* __restrict__ part,
                                                          const int* __restrict__ labels,
                                                          float* __restrict__ out) {
    __shared__ float th[CM];
    const int row = blockIdx.x;
    const int t = threadIdx.x;
    if (t < CM) {
        float s = 0.f;
        #pragma unroll
        for (int ks = 0; ks < KS; ++ks)
            s += part[((size_t)ks * NROW + row) * CM + t];
        th[t] = s;
    }
    __syncthreads();
    if (t < 64) {
        float v0 = (t < CC)       ? th[t]       : -INFINITY;
        float v1 = (t + 64 < CC)  ? th[t + 64]  : -INFINITY;
        float v2 = (t + 128 < CC) ? th[t + 128] : -INFINITY;
        float m = fmaxf(v0, fmaxf(v1, v2));
        #pragma unroll
        for (int o = 32; o > 0; o >>= 1) m = fmaxf(m, __shfl_xor(m, o, 64));
        float s = 0.f;
        if (t < CC)       s += expf(v0 - m);
        if (t + 64 < CC)  s += expf(v1 - m);
        if (t + 128 < CC) s += expf(v2 - m);
        #pragma unroll
        for (int o = 32; o > 0; o >>= 1) s += __shfl_xor(s, o, 64);
        if (t == 0) {
            atomicAdd(out, (m + logf(s) - th[labels[row]]) * (1.0f / NROW));
        }
    }
}

// ---------------------------------------------------------------------------
extern "C" void kernel_launch(void* const* d_in, const int* in_sizes, int n_in,
                              void* d_out, int out_size, void* d_ws, size_t ws_size,
                              hipStream_t stream) {
    // inputs: 0=roi_scores (unused), 1=rel_scores, 2=relationship_mat,
    //         3=roi_labels, 4=num_images (fixed B=4)
    const float* rel    = (const float*)d_in[1];
    const float* relmat = (const float*)d_in[2];
    const int*   labels = (const int*)d_in[3];
    float* out = (float*)d_out;
    char* ws = (char*)d_ws;

    _Float16* m1 = (_Float16*)(ws + OFF_M1);
    _Float16* m2 = (_Float16*)(ws + OFF_M2);
    float*  part = (float*)(ws + OFF_PT);

    prep_kernel<<<dim3(CC, 2), 256, 0, stream>>>(relmat, m1, m2, out);
    gemm_kernel<<<NB * 2 * KS, 512, 0, stream>>>(rel, m1, m2, labels, part);
    reduce_loss_kernel<<<NROW, 256, 0, stream>>>(part, labels, out);
}

// Round 10
// 170.263 us; speedup vs baseline: 1.0116x; 1.0116x over previous
//
#include <hip/hip_runtime.h>
#include <math.h>

#define NB 4
#define PP 256
#define CC 151
#define RR 51
#define CM 160                 // padded C (5 tiles of 32)
#define KS 64                  // split-K: 4 i's per block
#define NROW (NB*PP)           // 1024
#define RELTOT (NB*PP*PP*RR)   // 13,369,344 floats
#define ALIM (RELTOT - 8)
#define MLB 10240              // halves per l per mat: 8 oct * 160 c * 8 j
#define PER_HALVES (4*320*8)   // 10240 halves = 20 KB per period buffer

typedef _Float16 half8 __attribute__((ext_vector_type(8)));
typedef float floatx16 __attribute__((ext_vector_type(16)));

// ws layout (bytes): m1, m2, part
#define OFF_M1 ((size_t)0)
#define OFF_M2 (OFF_M1 + (size_t)CC*MLB*2)     // +3,092,480
#define OFF_PT (OFF_M2 + (size_t)CC*MLB*2)     // part: 64*1024*160*4 = 41.9 MB

// ---------------------------------------------------------------------------
// K1: streaming M layout. m1[l][oct][c][j] = w_r*M[l][c][oct*8+j],
// m2[l][oct][c][j] = w_r*M[c][l][oct*8+j]; r=oct*8+j; w_0=0.5 else 0.25;
// zero for r>=51 or c>=151 (zero rows make A's pad slots don't-care).
// ---------------------------------------------------------------------------
__global__ __launch_bounds__(256) void prep_kernel(const float* __restrict__ M,
                                                   _Float16* __restrict__ m1,
                                                   _Float16* __restrict__ m2,
                                                   float* __restrict__ out) {
    const int l = blockIdx.x;      // 0..150
    const int mat = blockIdx.y;    // 0,1
    if (l == 0 && mat == 0 && threadIdx.x == 0) *out = 0.f;
    _Float16* dst = (mat ? m2 : m1) + (size_t)l * MLB;
    for (int e = threadIdx.x; e < MLB; e += 256) {
        int oct = e / 1280;
        int rem = e - oct * 1280;
        int c = rem >> 3, j = rem & 7;
        int r = oct * 8 + j;
        float v = 0.f;
        if (r < RR && c < CC) {
            size_t src = ((size_t)(mat ? c * CC + l : l * CC + c)) * RR + r;
            v = (r == 0 ? 0.5f : 0.25f) * M[src];
        }
        dst[e] = (_Float16)v;
    }
}

// ---------------------------------------------------------------------------
// K2 (fused transpose+GEMM, 32x32x16 MFMA, period-pipelined):
// part[ks][q][c] = sum_{i in chunk, r} rel[n,i,q,r]*w_r*M[lab_i,c,r]   (mat0)
//                                    + rel[n,q,i,r]*w_r*M[c,lab_i,r]   (mat1)
// 8 PERIODS of 2 merged k16-steps. Per period: stage 20 KB of B (both mats,
// 2 t-tiles; 1280 contiguous 16B global_load_lds = 5/thread) into a 2x20KB
// double buffer, prefetch 32 A-floats/lane, then 40 MFMA. ONE barrier per
// period -> the compiler's vmcnt(0)-before-s_barrier drains loads issued a
// full period (~8000 cyc) earlier instead of killing the pipeline every
// 5 KB. Grid 512 = 4 img x 2 rowblk x 64 ks; 2 blocks/CU.
// ---------------------------------------------------------------------------
__global__ __launch_bounds__(256, 2) void gemm_kernel(const float* __restrict__ rel,
                                                      const _Float16* __restrict__ m1,
                                                      const _Float16* __restrict__ m2,
                                                      const int* __restrict__ labels,
                                                      float* __restrict__ part) {
    __shared__ _Float16 Bt[2][PER_HALVES];     // 2 x 20 KB
    const int tid  = threadIdx.x;
    const int ks   = blockIdx.x & 63;
    const int rbk  = (blockIdx.x >> 6) & 1;
    const int n    = blockIdx.x >> 7;
    const int wave = tid >> 6, lane = tid & 63;
    const int m32  = lane & 31, kh = lane >> 5;
    const int i0   = ks * 4;
    const int rowimg = rbk * 128 + wave * 32 + m32;   // lane's output row q

    int labs[4];
    #pragma unroll
    for (int j = 0; j < 4; ++j) labs[j] = labels[n * PP + i0 + j];

    floatx16 acc[5];
    #pragma unroll
    for (int ct = 0; ct < 5; ++ct)
        #pragma unroll
        for (int r2 = 0; r2 < 16; ++r2) acc[ct][r2] = 0.f;

    // period p in [0,8): il = p>>1; covers merged steps h = 2p, 2p+1
    // (t = h&3). Buffer layout: [(sub*2+mat)*320 + oct*160 + c] chunks of 8.
    auto stageB = [&](int p, int buf) {
        const int il = p >> 1;
        const size_t lbase = (size_t)labs[il] * MLB;
        #pragma unroll
        for (int j = 0; j < 5; ++j) {
            int s = j * 256 + tid;                 // 0..1279
            int sub = s >> 9;                      // /640
            int sm  = s - sub * 640;
            int mat = sm >= 320;
            int c320 = sm - mat * 320;
            int t = (2 * p + sub) & 3;
            const _Float16* g = (mat ? m2 : m1) + lbase + (size_t)t * 2560 + (size_t)c320 * 8;
            __builtin_amdgcn_global_load_lds(
                (const __attribute__((address_space(1))) unsigned int*)g,
                (__attribute__((address_space(3))) unsigned int*)(&Bt[buf][(size_t)s * 8]),
                16, 0, 0);
        }
    };
    // 32 A floats per lane per period: [sub][mat*8+j]
    auto loadA = [&](int p, float v[2][16]) {
        const int il = p >> 1;
        const int i = i0 + il;
        #pragma unroll
        for (int sub = 0; sub < 2; ++sub) {
            const int t = (2 * p + sub) & 3;
            const int r0 = t * 16 + kh * 8;
            int idx0 = ((n * PP + i) * PP + rowimg) * RR + r0;
            int idx1 = ((n * PP + rowimg) * PP + i) * RR + r0;
            idx0 = min(idx0, ALIM);   // clamp reachable only on i==q==255 diag
            idx1 = min(idx1, ALIM);
            const float* p0 = rel + idx0;
            const float* p1 = rel + idx1;
            #pragma unroll
            for (int j = 0; j < 8; ++j) { v[sub][j] = p0[j]; v[sub][8 + j] = p1[j]; }
        }
    };

    float av[2][16], avn[2][16];
    stageB(0, 0);
    loadA(0, av);

    for (int p = 0; p < 8; ++p) {
        __syncthreads();                    // Bt[p&1] resident (staged 1 period ago)
        if (p < 7) {
            stageB(p + 1, (p + 1) & 1);     // 20 KB in flight across this period
            loadA(p + 1, avn);
        }

        const bool dz = (i0 + (p >> 1)) == rowimg;   // diagonal i == q
        #pragma unroll
        for (int sub = 0; sub < 2; ++sub) {
            half8 a0, a1;
            #pragma unroll
            for (int j = 0; j < 8; ++j) {
                a0[j] = (_Float16)(dz ? 0.f : av[sub][j]);
                a1[j] = (_Float16)(dz ? 0.f : av[sub][8 + j]);
            }
            const _Float16* bb = &Bt[p & 1][(size_t)(sub * 640 + kh * 160 + m32) * 8];
            #pragma unroll
            for (int ct = 0; ct < 5; ++ct) {
                half8 b0 = *(const half8*)(bb + ct * 256);
                half8 b1 = *(const half8*)(bb + 2560 + ct * 256);
                acc[ct] = __builtin_amdgcn_mfma_f32_32x32x16_f16(a0, b0, acc[ct], 0, 0, 0);
                acc[ct] = __builtin_amdgcn_mfma_f32_32x32x16_f16(a1, b1, acc[ct], 0, 0, 0);
            }
        }
        #pragma unroll
        for (int sub = 0; sub < 2; ++sub)
            #pragma unroll
            for (int j = 0; j < 16; ++j) av[sub][j] = avn[sub][j];
    }

    // C/D 32x32 layout (m74/m101): col = m32, row = (reg&3)+8*(reg>>2)+4*kh
    float* pb = part + ((size_t)ks * NROW + n * PP + rbk * 128 + wave * 32) * CM;
    #pragma unroll
    for (int ct = 0; ct < 5; ++ct)
        #pragma unroll
        for (int reg = 0; reg < 16; ++reg) {
            int row = (reg & 3) + 8 * (reg >> 2) + 4 * kh;
            pb[(size_t)row * CM + ct * 32 + m32] = acc[ct][reg];
        }
}

// ---------------------------------------------------------------------------
// K3: theta[row][c] = sum_ks part; loss = lse(theta) - theta[lab]; mean.
// ---------------------------------------------------------------------------
__global__ __launch_bounds__(256) void reduce_loss_kernel(const float* __restrict__ part,
                                                          const int* __restrict__ labels,
                                                          float* __restrict__ out) {
    __shared__ float th[CM];
    const int row = blockIdx.x;
    const int t = threadIdx.x;
    if (t < CM) {
        float s = 0.f;
        #pragma unroll
        for (int ks = 0; ks < KS; ++ks)
            s += part[((size_t)ks * NROW + row) * CM + t];
        th[t] = s;
    }
    __syncthreads();
    if (t < 64) {
        float v0 = (t < CC)       ? th[t]       : -INFINITY;
        float v1 = (t + 64 < CC)  ? th[t + 64]  : -INFINITY;
        float v2 = (t + 128 < CC) ? th[t + 128] : -INFINITY;
        float m = fmaxf(v0, fmaxf(v1, v2));
        #pragma unroll
        for (int o = 32; o > 0; o >>= 1) m = fmaxf(m, __shfl_xor(m, o, 64));
        float s = 0.f;
        if (t < CC)       s += expf(v0 - m);
        if (t + 64 < CC)  s += expf(v1 - m);
        if (t + 128 < CC) s += expf(v2 - m);
        #pragma unroll
        for (int o = 32; o > 0; o >>= 1) s += __shfl_xor(s, o, 64);
        if (t == 0) {
            atomicAdd(out, (m + logf(s) - th[labels[row]]) * (1.0f / NROW));
        }
    }
}

// ---------------------------------------------------------------------------
extern "C" void kernel_launch(void* const* d_in, const int* in_sizes, int n_in,
                              void* d_out, int out_size, void* d_ws, size_t ws_size,
                              hipStream_t stream) {
    // inputs: 0=roi_scores (unused), 1=rel_scores, 2=relationship_mat,
    //         3=roi_labels, 4=num_images (fixed B=4)
    const float* rel    = (const float*)d_in[1];
    const float* relmat = (const float*)d_in[2];
    const int*   labels = (const int*)d_in[3];
    float* out = (float*)d_out;
    char* ws = (char*)d_ws;

    _Float16* m1 = (_Float16*)(ws + OFF_M1);
    _Float16* m2 = (_Float16*)(ws + OFF_M2);
    float*  part = (float*)(ws + OFF_PT);

    prep_kernel<<<dim3(CC, 2), 256, 0, stream>>>(relmat, m1, m2, out);
    gemm_kernel<<<NB * 2 * KS, 256, 0, stream>>>(rel, m1, m2, labels, part);
    reduce_loss_kernel<<<NROW, 256, 0, stream>>>(part, labels, out);
}